// Round 11
// baseline (260.336 us; speedup 1.0000x reference)
//
#include <hip/hip_runtime.h>
#include <hip/hip_bf16.h>

#define Bb  8
#define Cc  64
#define Tt  16
#define Vv  207
#define Hh  8
#define DH  8
#define NW  4
#define WSZ 4
#define Nn  (WSZ*Vv)       // 828
#define TV  (Tt*Vv)        // 3312
#define CTV (Cc*Tt*Vv)     // 211968
#define S   (Bb*CTV)       // 1695744
#define NBWH (Bb*NW*Hh)    // 256
#define EPSF 1e-5f
#define QSCALE 0.51006971401146f    // log2(e)/sqrt(8) folded into Q
#define FRAG_BWH (52*64*4)          // 13312 shorts per bwh
#define WFU 21504                    // total weight-frag units (bf16x4) in global

typedef __attribute__((ext_vector_type(4))) short bf16x4;
typedef __attribute__((ext_vector_type(4))) float f32x4;
typedef __attribute__((ext_vector_type(2))) unsigned int u32x2;
typedef __attribute__((ext_vector_type(4))) unsigned int u32x4;

static __device__ __forceinline__ short f2bf(float f) {
    union { float f; unsigned u; } v; v.f = f;
    unsigned r = (v.u + 0x7FFFu + ((v.u >> 16) & 1u)) >> 16;  // RNE
    return (short)r;
}

// cheap pack: round-half-up (bias cancels in softmax; fine elsewhere too) — R2-proven
static __device__ __forceinline__ bf16x4 pack4(float a, float b, float c, float d) {
    unsigned ua = __builtin_bit_cast(unsigned, a) + 0x8000u;
    unsigned ub = __builtin_bit_cast(unsigned, b) + 0x8000u;
    unsigned uc = __builtin_bit_cast(unsigned, c) + 0x8000u;
    unsigned ud = __builtin_bit_cast(unsigned, d) + 0x8000u;
    u32x2 t;
    t[0] = (ua >> 16) | (ub & 0xFFFF0000u);
    t[1] = (uc >> 16) | (ud & 0xFFFF0000u);
    return __builtin_bit_cast(bf16x4, t);
}

// truncating pack via byte-perm — softmax P only (num & denom share truncation)
static __device__ __forceinline__ bf16x4 pack4_trunc(float a, float b, float c, float d) {
    unsigned ea = __builtin_bit_cast(unsigned, a);
    unsigned eb = __builtin_bit_cast(unsigned, b);
    unsigned ec = __builtin_bit_cast(unsigned, c);
    unsigned ed = __builtin_bit_cast(unsigned, d);
    u32x2 t;
    t[0] = __builtin_amdgcn_perm(eb, ea, 0x07060302u);
    t[1] = __builtin_amdgcn_perm(ed, ec, 0x07060302u);
    return __builtin_bit_cast(bf16x4, t);
}

// wave-level stats reduce: 6 shfl_down pairs, one LDS slot per wave, ONE barrier.
static __device__ __forceinline__ void stats_reduce(float s1, float s2, float* r1, float* r2,
                                                    int tid, int lane, int wv,
                                                    float* __restrict__ stats, int b) {
    #pragma unroll
    for (int o = 32; o > 0; o >>= 1) {
        s1 += __shfl_down(s1, o, 64);
        s2 += __shfl_down(s2, o, 64);
    }
    if (lane == 0) { r1[wv] = s1; r2[wv] = s2; }
    __syncthreads();
    if (tid == 0) {
        float t1 = 0.f, t2 = 0.f;
        #pragma unroll
        for (int i = 0; i < 8; ++i) { t1 += r1[i]; t2 += r2[i]; }
        atomicAdd(&stats[b*2], t1); atomicAdd(&stats[b*2+1], t2);
    }
}

// ---------------- QKV: MFMA GEMM (+fused LN2+roll); LA: LDS-staged weights + global init ----------------
// grid = 416 blocks, 512 threads (8 waves: 4 row-subtiles x 2 nt-halves)
template<bool LA>
__global__ __launch_bounds__(512) void qkv_kernel(const float* __restrict__ src,
        const float* __restrict__ st, const float* __restrict__ g, const float* __restrict__ be,
        const float* __restrict__ qw,       // LA: raw f32 [C][3C]
        const short* __restrict__ wfq,      // !LA: global bf16 frags (3072 units)
        const float* __restrict__ bias,
        short* __restrict__ qf, short* __restrict__ kf, short* __restrict__ vf,
        float* __restrict__ stats,
        // LA-only: sources for downstream weight-frag conversion
        const float* __restrict__ pA, const float* __restrict__ w1A, const float* __restrict__ w2A,
        const float* __restrict__ qwB, const float* __restrict__ pB,
        const float* __restrict__ w1B, const float* __restrict__ w2B,
        short* __restrict__ wfg) {
    __shared__ short wqs[LA ? 12288 : 64];   // 24 KB weight frags (LA only)
    __shared__ short os[64*196];             // 24.5 KB transpose buffer [pos][ch]
    int tid = threadIdx.x;
    int b = blockIdx.x / 52;
    int r0 = (blockIdx.x % 52) * 64;
    const float* xb = src + (size_t)b*CTV;

    int lane = tid & 63; int wv = tid >> 6;     // 0..7
    int rs = wv & 3; int gsel = wv >> 2;        // row subtile / nt-half
    int l15 = lane & 15; int quad = lane >> 4;
    int r = r0 + rs*16 + l15;
    int rc = (r < TV) ? r : TV-1;
    int t = rc / Vv; int vv = rc - t*Vv;
    float mean = 0.f, rstd = 0.f; int off;
    if (!LA) {
        mean = st[b*2] * (1.0f/CTV);
        float var = st[b*2+1] * (1.0f/CTV) - mean*mean;
        rstd = rsqrtf(var + EPSF);
        off = ((t+2)&15)*Vv + vv;       // roll(-2): read source at t+2
    } else off = rc;

    // x fragment FIRST: issue global loads early
    bf16x4 xf[4];
    #pragma unroll
    for (int kc = 0; kc < 4; ++kc) {
        #pragma unroll
        for (int j = 0; j < 4; ++j) {
            int idx = (kc*16 + quad*4 + j)*TV + off;
            float x0 = xb[idx];
            if (!LA) x0 = (x0 - mean)*rstd*g[idx] + be[idx];
            xf[kc][j] = f2bf(x0);
        }
    }

    if constexpr (LA) {
        // own weights -> LDS frags
        for (int fs = tid; fs < 3072; fs += 512) {
            int nt = fs >> 8; int kc = (fs >> 6) & 3; int ln = fs & 63;
            int li = ln & 15; int q = ln >> 4;
            bf16x4 o;
            #pragma unroll
            for (int j = 0; j < 4; ++j) o[j] = f2bf(qw[(kc*16 + q*4 + j)*192 + nt*16 + li]);
            *((bf16x4*)&wqs[fs*4]) = o;
        }
        if (blockIdx.x == 0 && tid < 64) stats[tid] = 0.f;
        // downstream weight frags -> GLOBAL (done once; consumed by later kernels via L2)
        for (int i = blockIdx.x*512 + tid; i < WFU; i += 416*512) {
            int s, kind; const float* sp;
            if (i < 1024)       { s = i;        sp = pA;  kind = 0; }
            else if (i < 5120)  { s = i-1024;   sp = w1A; kind = 1; }
            else if (i < 9216)  { s = i-5120;   sp = w2A; kind = 2; }
            else if (i < 12288) { s = i-9216;   sp = qwB; kind = 3; }
            else if (i < 13312) { s = i-12288;  sp = pB;  kind = 0; }
            else if (i < 17408) { s = i-13312;  sp = w1B; kind = 1; }
            else                { s = i-17408;  sp = w2B; kind = 2; }
            int nt = s >> 8; int kc = (s >> 6) & 3; int ln = s & 63;
            int li = ln & 15; int q = ln >> 4;
            bf16x4 o;
            #pragma unroll
            for (int j = 0; j < 4; ++j) {
                int sidx;
                if (kind == 0)      sidx = (kc*16 + q*4 + j)*64  + nt*16 + li;
                else if (kind == 1) sidx = (kc*16 + q*4 + j)*256 + nt*16 + li;
                else if (kind == 2) sidx = (nt*16 + q*4 + j)*64  + kc*16 + li;
                else                sidx = (kc*16 + q*4 + j)*192 + nt*16 + li;
                o[j] = f2bf(sp[sidx]);
            }
            *((bf16x4*)&wfg[i*4]) = o;
        }
        // frag pad constants (all addresses attn reads must be DEFINED)
        for (int i = blockIdx.x*512 + tid; i < NBWH*1664; i += 416*512) {
            int bwh = i / 1664; int rest = i % 1664;
            int nt = rest >> 5; int u = rest & 31;
            size_t base = (size_t)bwh*FRAG_BWH + nt*256;
            *((u32x2*)&qf[base + (32+u)*4]) = (u32x2){0u, 0u};
            *((u32x2*)&kf[base + (32+u)*4]) = (u32x2){0u, 0u};
            int vlane = (u>>3)*16 + 8 + (u&7);
            short v = ((u&7) == 0) ? (short)0x3F80 : (short)0;
            bf16x4 vv4 = {v,v,v,v};
            *((bf16x4*)&vf[base + vlane*4]) = vv4;
            if (nt == 51) {
                bf16x4 z4 = {0,0,0,0};
                if (u < 4) {
                    *((bf16x4*)&kf[base + (12+u)*4]) = z4;
                    *((bf16x4*)&qf[base + (12+u)*4]) = z4;
                } else if (u < 8) {
                    *((bf16x4*)&kf[base + (24+u)*4]) = z4;
                    *((bf16x4*)&qf[base + (24+u)*4]) = z4;
                } else if (u < 16) {
                    *((bf16x4*)&vf[base + (40+u)*4]) = z4;
                }
            }
        }
        __syncthreads();   // wqs ready
    }

    f32x4 accv[6];
    #pragma unroll
    for (int ntl = 0; ntl < 6; ++ntl) {
        int nt = gsel*6 + ntl;
        float4 bb = *((const float4*)&bias[nt*16 + quad*4]);
        f32x4 acc = {bb.x, bb.y, bb.z, bb.w};
        #pragma unroll
        for (int kc = 0; kc < 4; ++kc) {
            bf16x4 wf2;
            if constexpr (LA) wf2 = *((const bf16x4*)&wqs[((nt*4 + kc)*64 + lane)*4]);
            else              wf2 = *((const bf16x4*)&wfq[((size_t)((nt*4 + kc)*64 + lane))*4]);
            acc = __builtin_amdgcn_mfma_f32_16x16x16bf16_1k(wf2, xf[kc], acc, 0, 0, 0);
        }
        accv[ntl] = acc;
    }

    // transpose to LDS: os[pos*196 + ch], ch = nt*16 + quad*4 + j
    int pos = rs*16 + l15;
    #pragma unroll
    for (int ntl = 0; ntl < 6; ++ntl) {
        int nt = gsel*6 + ntl;
        f32x4 a = accv[ntl];
        bf16x4 pk = (nt < 4) ? pack4(a[0]*QSCALE, a[1]*QSCALE, a[2]*QSCALE, a[3]*QSCALE)
                             : pack4(a[0], a[1], a[2], a[3]);
        *((bf16x4*)&os[pos*196 + nt*16 + quad*4]) = pk;
    }
    __syncthreads();

    // store phase: frag-ordered outputs; 8 waves -> h = wv for q/k
    int pp = tid & 63;
    int rr = r0 + pp;
    bool pv = rr < TV;
    int rrc = pv ? rr : TV-1;
    int t4 = rrc / Vv; int vv4 = rrc - t4*Vv;
    int n2 = (t4 & 3)*Vv + vv4;
    int nt2 = n2 >> 4; int l15n = n2 & 15;
    int wbase = (b*NW + (t4 >> 2))*Hh;
    if (pv) {
        int h = wv;
        size_t fb = ((size_t)(wbase+h)*52 + nt2)*256;
        bf16x4 q0 = *((const bf16x4*)&os[pp*196 + h*8]);
        bf16x4 q1 = *((const bf16x4*)&os[pp*196 + h*8 + 4]);
        *((bf16x4*)&qf[fb + l15n*4])        = q0;
        *((bf16x4*)&qf[fb + (16 + l15n)*4]) = q1;
        bf16x4 k0 = *((const bf16x4*)&os[pp*196 + 64 + h*8]);
        bf16x4 k1 = *((const bf16x4*)&os[pp*196 + 64 + h*8 + 4]);
        *((bf16x4*)&kf[fb + l15n*4])        = k0;
        *((bf16x4*)&kf[fb + (16 + l15n)*4]) = k1;
    }
    // v store: vectorized 4-row quads (828 % 4 == 0 so quads never straddle windows)
    #pragma unroll
    for (int u2 = 0; u2 < 2; ++u2) {
        int unit = u2*512 + tid;
        int rq = unit >> 6;          // 0..15
        int hd = unit & 63;
        int r4 = r0 + rq*4;
        if (r4 < TV) {
            int w = r4 / Nn;
            int n = r4 - w*Nn;
            int nt2v = n >> 4; int quadv = (n >> 2) & 3;
            int h = hd >> 3; int d = hd & 7;
            int posb = rq*4;
            bf16x4 vo;
            vo[0] = os[(posb+0)*196 + 128 + hd];
            vo[1] = os[(posb+1)*196 + 128 + hd];
            vo[2] = os[(posb+2)*196 + 128 + hd];
            vo[3] = os[(posb+3)*196 + 128 + hd];
            *((bf16x4*)&vf[((((size_t)(b*NW + w)*Hh + h)*52 + nt2v)*64 + quadv*16 + d)*4]) = vo;
        }
    }
}

// ---------------- Flash MFMA attention: aq prefetch + peeled mask + 2x-unrolled main loop ----------------
// grid = 256 blocks, 1024 threads (16 waves; wave wv owns m-tiles wv+16*i)
__global__ __launch_bounds__(1024) void attn_kernel(const short* __restrict__ qf,
        const short* __restrict__ kf, const short* __restrict__ vf,
        short* __restrict__ att) {
    __shared__ short ks2[FRAG_BWH];   // 26.6 KB
    __shared__ short vs2[FRAG_BWH];   // 26.6 KB
    int bwh = blockIdx.x;
    int tid = threadIdx.x;
    int lane = tid & 63;
    int wv = tid >> 6;
    int quad = lane >> 4;
    int l15 = lane & 15;

    // aq prefetch FIRST: Q-frag loads issue before staging so HBM latency hides under it
    int nm = (wv < 4) ? 4 : 3;
    const short* qbase = qf + (size_t)bwh*FRAG_BWH;
    bf16x4 aq[4];
    f32x4 oacc[4];
    #pragma unroll
    for (int i = 0; i < 4; ++i) {
        aq[i] = (bf16x4){0,0,0,0};
        oacc[i] = (f32x4){0.f,0.f,0.f,0.f};
        if (i < nm)
            aq[i] = *(const bf16x4*)(qbase + ((wv + 16*i)*256 + lane*4));
    }

    {
        const u32x4* kg = (const u32x4*)(kf + (size_t)bwh*FRAG_BWH);
        const u32x4* vg = (const u32x4*)(vf + (size_t)bwh*FRAG_BWH);
        u32x4* kd = (u32x4*)ks2; u32x4* vd = (u32x4*)vs2;
        for (int idx = tid; idx < 1664; idx += 1024) { kd[idx] = kg[idx]; vd[idx] = vg[idx]; }
    }
    __syncthreads();

    // main loop: nt = 0..50, mask-free; unroll 2 lets the scheduler hoist
    // the next iteration's ds_reads above this iteration's exp/PV tail
    #pragma unroll 2
    for (int nt = 0; nt < 51; ++nt) {
        bf16x4 ak = *(const bf16x4*)&ks2[nt*256 + lane*4];
        bf16x4 av = *(const bf16x4*)&vs2[nt*256 + lane*4];
        #pragma unroll
        for (int i = 0; i < 4; ++i) {
            if (i < nm) {
                f32x4 s = __builtin_amdgcn_mfma_f32_16x16x16bf16_1k(
                              ak, aq[i], (f32x4){0.f,0.f,0.f,0.f}, 0, 0, 0);
                bf16x4 pb = pack4_trunc(__builtin_amdgcn_exp2f(s[0]), __builtin_amdgcn_exp2f(s[1]),
                                        __builtin_amdgcn_exp2f(s[2]), __builtin_amdgcn_exp2f(s[3]));
                oacc[i] = __builtin_amdgcn_mfma_f32_16x16x16bf16_1k(av, pb, oacc[i], 0, 0, 0);
            }
        }
    }
    // peeled tail: nt = 51 with pad-key mask (keys n=828..831 live in quad 3)
    {
        bf16x4 ak = *(const bf16x4*)&ks2[51*256 + lane*4];
        bf16x4 av = *(const bf16x4*)&vs2[51*256 + lane*4];
        bool mask = (quad == 3);
        #pragma unroll
        for (int i = 0; i < 4; ++i) {
            if (i < nm) {
                f32x4 s = __builtin_amdgcn_mfma_f32_16x16x16bf16_1k(
                              ak, aq[i], (f32x4){0.f,0.f,0.f,0.f}, 0, 0, 0);
                bf16x4 pb = pack4_trunc(__builtin_amdgcn_exp2f(s[0]), __builtin_amdgcn_exp2f(s[1]),
                                        __builtin_amdgcn_exp2f(s[2]), __builtin_amdgcn_exp2f(s[3]));
                if (mask) pb = (bf16x4){0,0,0,0};
                oacc[i] = __builtin_amdgcn_mfma_f32_16x16x16bf16_1k(av, pb, oacc[i], 0, 0, 0);
            }
        }
    }
    int h = bwh & 7; int bw = bwh >> 3;
    #pragma unroll
    for (int i = 0; i < 4; ++i) {
        if (i < nm) {
            float ls = __shfl(oacc[i][0], 32 + l15, 64);   // l-sum = O row 8
            float inv = 1.f / ls;
            int m = (wv + 16*i)*16 + l15;
            if (quad < 2 && m < Nn) {
                bf16x4 ov = pack4(oacc[i][0]*inv, oacc[i][1]*inv,
                                  oacc[i][2]*inv, oacc[i][3]*inv);
                *((bf16x4*)&att[((size_t)bw*Nn + m)*Cc + h*DH + quad*4]) = ov;
            }
        }
    }
}

// ---------------- Proj: global weight frags; residual hoist; shuffle stats reduce ----------------
__global__ __launch_bounds__(512) void proj_kernel(const short* __restrict__ att,
        const short* __restrict__ wfp, const float* __restrict__ bo,
        const float* __restrict__ resid,
        const float* __restrict__ st, const float* __restrict__ g, const float* __restrict__ be,
        float* __restrict__ out, float* __restrict__ stats) {
    __shared__ float r1[8], r2[8];
    int tid = threadIdx.x;
    int b = blockIdx.x / 52;
    int r0 = (blockIdx.x % 52) * 64;
    const float* xb = resid + (size_t)b*CTV;

    int lane = tid & 63; int wv = tid >> 6;
    int rs = wv & 3; int gsel = wv >> 2;
    int l15 = lane & 15; int quad = lane >> 4;
    int r = r0 + rs*16 + l15;
    bool valid = r < TV;
    int rc = valid ? r : TV-1;
    int t = rc / Vv; int vv = rc - t*Vv;
    int n = (t & 3)*Vv + vv;
    int bw = b*NW + (t >> 2);

    // LN params + residual offset EARLY (so residual loads can hoist)
    float mean = 0.f, rstd = 0.f; int off;
    if (st) {
        mean = st[b*2] * (1.0f/CTV);
        float var = st[b*2+1] * (1.0f/CTV) - mean*mean;
        rstd = rsqrtf(var + EPSF);
        off = ((t+2)&15)*Vv + vv;
    } else off = rc;

    // att loads (MFMA A-operand)
    const short* arow = att + ((size_t)bw*Nn + n)*Cc;
    bf16x4 af[4];
    #pragma unroll
    for (int kc = 0; kc < 4; ++kc)
        af[kc] = *((const bf16x4*)&arow[kc*16 + quad*4]);

    // residual prefetch: independent loads issued BEFORE the MFMA chain
    float xr[8], gr[8], ber[8];
    #pragma unroll
    for (int ntl = 0; ntl < 2; ++ntl) {
        #pragma unroll
        for (int j = 0; j < 4; ++j) {
            int c_out = (gsel*2 + ntl)*16 + quad*4 + j;
            int ridx = c_out*TV + off;
            int u = ntl*4 + j;
            xr[u] = xb[ridx];
            if (st) { gr[u] = g[ridx]; ber[u] = be[ridx]; }
        }
    }

    f32x4 acc[2];
    #pragma unroll
    for (int ntl = 0; ntl < 2; ++ntl) {
        int nt = gsel*2 + ntl;
        float4 bb = *((const float4*)&bo[nt*16 + quad*4]);
        acc[ntl] = (f32x4){bb.x, bb.y, bb.z, bb.w};
        #pragma unroll
        for (int kc = 0; kc < 4; ++kc) {
            bf16x4 wf2 = *((const bf16x4*)&wfp[((size_t)((nt*4 + kc)*64 + lane))*4]);
            acc[ntl] = __builtin_amdgcn_mfma_f32_16x16x16bf16_1k(wf2, af[kc], acc[ntl], 0, 0, 0);
        }
    }

    float s1 = 0.f, s2 = 0.f;
    if (valid) {
        #pragma unroll
        for (int ntl = 0; ntl < 2; ++ntl) {
            int nt = gsel*2 + ntl;
            #pragma unroll
            for (int j = 0; j < 4; ++j) {
                int c_out = nt*16 + quad*4 + j;
                int u = ntl*4 + j;
                float xv = xr[u];
                if (st) xv = (xv - mean)*rstd*gr[u] + ber[u];
                float val = acc[ntl][j] + xv;
                out[(size_t)b*CTV + (size_t)c_out*TV + r] = val;
                s1 += val; s2 += val*val;
            }
        }
    }
    stats_reduce(s1, s2, r1, r2, tid, lane, wv, stats, b);
}

// ---------------- LayerNorm apply (+roll) — final output only; 4 elems/thread ----------------
__global__ void ln_apply_kernel(const float* __restrict__ x,
                                const float* __restrict__ g,
                                const float* __restrict__ be,
                                const float* __restrict__ stats,
                                float* __restrict__ out) {
    int i4 = (blockIdx.x*256 + threadIdx.x) * 4;
    if (i4 >= S) return;
    int b = i4 / CTV; int r = i4 % CTV;
    int c = r / TV; int q2 = r % TV; int t = q2 / Vv; int vv = q2 - t*Vv;
    float mean = stats[b*2] * (1.0f/CTV);
    float var  = stats[b*2+1] * (1.0f/CTV) - mean*mean;
    float rstd = rsqrtf(var + EPSF);
    float4 xv = *((const float4*)&x[i4]);
    float vals[4] = {xv.x, xv.y, xv.z, xv.w};
    size_t obase = (size_t)(b*Cc + c)*Tt;
    #pragma unroll
    for (int j = 0; j < 4; ++j) {
        float val = (vals[j]-mean)*rstd*g[r+j] + be[r+j];
        int tout = (t - 2 + Tt) & 15;   // roll(-2)
        out[(obase + tout)*Vv + vv] = val;
        if (++vv == Vv) { vv = 0; ++t; }
    }
}

// ---------------- FFN: global weight frags; conflict-free f32 LN(x) cache for epilogue ----------------
__global__ __launch_bounds__(512) void ffn_kernel(const float* __restrict__ xin,
        const float* __restrict__ st, const float* __restrict__ g, const float* __restrict__ be,
        const short* __restrict__ wf1g, const float* __restrict__ b1,
        const short* __restrict__ wf2g, const float* __restrict__ b2,
        float* __restrict__ out, float* __restrict__ stats) {
    __shared__ short xsf[4096];     // 8 KB bf16 frags
    __shared__ float xsl[4*1024];   // 16 KB f32 LN(x) cache, [j][unit] layout (conflict-free)
    __shared__ float r1s[8], r2s[8];
    int tid = threadIdx.x;
    int b = blockIdx.x / 52;
    int r0 = (blockIdx.x % 52) * 64;
    const float* xb = xin + (size_t)b*CTV;
    float mean = st[b*2] * (1.0f/CTV);
    float var  = st[b*2+1] * (1.0f/CTV) - mean*mean;
    float rstd = rsqrtf(var + EPSF);

    // x staging (LN1 fused): bf16 frags + f32 cache in [j][unit] layout
    // (lane-consecutive unit => stride-1 banks on both write and read)
    for (int s2 = tid; s2 < 1024; s2 += 512) {
        int wv2 = s2 >> 8; int kc = (s2 >> 6) & 3; int ln = s2 & 63;
        int l15 = ln & 15; int quad = ln >> 4;
        int r = r0 + wv2*16 + l15; if (r >= TV) r = TV-1;
        bf16x4 f;
        #pragma unroll
        for (int j = 0; j < 4; ++j) {
            int idx = (kc*16 + quad*4 + j)*TV + r;
            float xv = (xb[idx] - mean)*rstd*g[idx] + be[idx];
            xsl[j*1024 + s2] = xv;
            f[j] = f2bf(xv);
        }
        *((bf16x4*)&xsf[s2*4]) = f;
    }
    __syncthreads();

    int lane = tid & 63; int wv = tid >> 6;
    int rs = wv & 3; int gsel = wv >> 2;
    int l15 = lane & 15; int quad = lane >> 4;
    bf16x4 xf[4];
    #pragma unroll
    for (int kc = 0; kc < 4; ++kc)
        xf[kc] = *((const bf16x4*)&xsf[((rs*4 + kc)*64 + lane)*4]);

    f32x4 oacc[2];
    #pragma unroll
    for (int ctl = 0; ctl < 2; ++ctl) oacc[ctl] = (f32x4){0.f,0.f,0.f,0.f};

    for (int nt = 0; nt < 16; ++nt) {
        float4 bb = *((const float4*)&b1[nt*16 + quad*4]);
        f32x4 acc = {bb.x, bb.y, bb.z, bb.w};
        #pragma unroll
        for (int kc = 0; kc < 4; ++kc) {
            bf16x4 wfv = *((const bf16x4*)&wf1g[((size_t)((nt*4 + kc)*64 + lane))*4]);
            acc = __builtin_amdgcn_mfma_f32_16x16x16bf16_1k(wfv, xf[kc], acc, 0, 0, 0);
        }
        bf16x4 pf = pack4(fmaxf(acc[0], 0.f), fmaxf(acc[1], 0.f),
                          fmaxf(acc[2], 0.f), fmaxf(acc[3], 0.f));
        #pragma unroll
        for (int ctl = 0; ctl < 2; ++ctl) {
            int ct = gsel*2 + ctl;
            bf16x4 wfv2 = *((const bf16x4*)&wf2g[((size_t)((nt*4 + ct)*64 + lane))*4]);
            oacc[ctl] = __builtin_amdgcn_mfma_f32_16x16x16bf16_1k(wfv2, pf, oacc[ctl], 0, 0, 0);
        }
    }
    int r = r0 + rs*16 + l15;
    float s1 = 0.f, s2v = 0.f;
    if (r < TV) {
        #pragma unroll
        for (int ctl = 0; ctl < 2; ++ctl) {
            int ct = gsel*2 + ctl;
            int unit = (rs*4 + ct)*64 + quad*16 + l15;
            #pragma unroll
            for (int j = 0; j < 4; ++j) {
                int c_out = ct*16 + quad*4 + j;
                // residual from conflict-free LDS cache (bitwise-identical to re-LN)
                float xv = xsl[j*1024 + unit];
                float val = oacc[ctl][j] + b2[c_out] + xv;
                out[(size_t)b*CTV + (size_t)c_out*TV + r] = val;
                s1 += val; s2v += val*val;
            }
        }
    }
    stats_reduce(s1, s2v, r1s, r2s, tid, lane, wv, stats, b);
}

extern "C" void kernel_launch(void* const* d_in, const int* in_sizes, int n_in,
                              void* d_out, int out_size, void* d_ws, size_t ws_size,
                              hipStream_t stream) {
    const float* xin = (const float*)d_in[0];

    float* bufA  = (float*)d_ws;
    float* bufB  = bufA + S;
    float* stats = bufB + S;                        // 64 floats
    short* qf    = (short*)(stats + 64);            // [NBWH][52][64][4]
    short* kf    = qf + (size_t)NBWH*FRAG_BWH;
    short* vf    = kf + (size_t)NBWH*FRAG_BWH;
    short* att   = vf + (size_t)NBWH*FRAG_BWH;      // [32][Nn][64] bf16
    short* wfg   = att + (size_t)32*Nn*64;          // 21504 bf16x4 weight-frag units

    const float* A0  = (const float*)d_in[1];
    const float* A1  = (const float*)d_in[2];
    const float* A2  = (const float*)d_in[3];
    const float* A3  = (const float*)d_in[4];
    const float* A4  = (const float*)d_in[5];
    const float* A5  = (const float*)d_in[6];
    const float* A6  = (const float*)d_in[7];
    const float* A7  = (const float*)d_in[8];
    const float* A8  = (const float*)d_in[9];
    const float* A9  = (const float*)d_in[10];
    const float* A10 = (const float*)d_in[11];
    const float* A11 = (const float*)d_in[12];
    const float* B0  = (const float*)d_in[13];
    const float* B1  = (const float*)d_in[14];
    const float* B2  = (const float*)d_in[15];
    const float* B3  = (const float*)d_in[16];
    const float* B4  = (const float*)d_in[17];
    const float* B5  = (const float*)d_in[18];
    const float* B6  = (const float*)d_in[19];
    const float* B7  = (const float*)d_in[20];
    const float* B8  = (const float*)d_in[21];
    const float* B9  = (const float*)d_in[22];
    const float* B10 = (const float*)d_in[23];
    const float* B11 = (const float*)d_in[24];

    float* st1a = stats + 0;
    float* st2a = stats + 16;
    float* st1b = stats + 32;
    float* st2b = stats + 48;

    // global frag offsets (shorts)
    const short* wprojA = wfg;              // units @0
    const short* w1Ag   = wfg + 4096;       // @1024
    const short* w2Ag   = wfg + 20480;      // @5120
    const short* wqkvB  = wfg + 36864;      // @9216
    const short* wprojB = wfg + 49152;      // @12288
    const short* w1Bg   = wfg + 53248;      // @13312
    const short* w2Bg   = wfg + 69632;      // @17408

    // ---- block A (input raw) ----
    qkv_kernel<true><<<Bb*52, 512, 0, stream>>>(xin, nullptr, nullptr, nullptr,
                                          A0, nullptr, A1, qf, kf, vf, stats,
                                          A2, A4, A6, B0, B2, B4, B6, wfg);
    attn_kernel<<<NBWH, 1024, 0, stream>>>(qf, kf, vf, att);
    proj_kernel<<<Bb*52, 512, 0, stream>>>(att, wprojA, A3, xin,
                                           nullptr, nullptr, nullptr, bufB, st1a);
    ffn_kernel<<<Bb*52, 512, 0, stream>>>(bufB, st1a, A8, A9,
                                          w1Ag, A5, w2Ag, A7, bufB, st2a);
    // ---- block B (input = LN_a2(bufB) rolled, fused into consumers) ----
    qkv_kernel<false><<<Bb*52, 512, 0, stream>>>(bufB, st2a, A10, A11,
                                          nullptr, wqkvB, B1, qf, kf, vf, stats,
                                          nullptr, nullptr, nullptr, nullptr,
                                          nullptr, nullptr, nullptr, nullptr);
    attn_kernel<<<NBWH, 1024, 0, stream>>>(qf, kf, vf, att);
    proj_kernel<<<Bb*52, 512, 0, stream>>>(att, wprojB, B3, bufB,
                                           st2a, A10, A11, bufA, st1b);
    ffn_kernel<<<Bb*52, 512, 0, stream>>>(bufA, st1b, B8, B9,
                                          w1Bg, B5, w2Bg, B7, bufA, st2b);
    // ---- final LN_b2 + roll -> d_out ----
    ln_apply_kernel<<<(S/4+255)/256, 256, 0, stream>>>(bufA, B10, B11, st2b, (float*)d_out);
}

// Round 13
// 259.134 us; speedup vs baseline: 1.0046x; 1.0046x over previous
//
#include <hip/hip_runtime.h>
#include <hip/hip_bf16.h>

#define Bb  8
#define Cc  64
#define Tt  16
#define Vv  207
#define Hh  8
#define DH  8
#define NW  4
#define WSZ 4
#define Nn  (WSZ*Vv)       // 828
#define TV  (Tt*Vv)        // 3312
#define CTV (Cc*Tt*Vv)     // 211968
#define S   (Bb*CTV)       // 1695744
#define NBWH (Bb*NW*Hh)    // 256
#define EPSF 1e-5f
#define QSCALE 0.51006971401146f    // log2(e)/sqrt(8) folded into Q
#define FRAG_BWH (52*64*4)          // 13312 shorts per bwh
#define WFU 21504                    // total weight-frag units (bf16x4) in global

typedef __attribute__((ext_vector_type(4))) short bf16x4;
typedef __attribute__((ext_vector_type(4))) float f32x4;
typedef __attribute__((ext_vector_type(2))) unsigned int u32x2;
typedef __attribute__((ext_vector_type(4))) unsigned int u32x4;

static __device__ __forceinline__ short f2bf(float f) {
    union { float f; unsigned u; } v; v.f = f;
    unsigned r = (v.u + 0x7FFFu + ((v.u >> 16) & 1u)) >> 16;  // RNE
    return (short)r;
}

// cheap pack: round-half-up (bias cancels in softmax; fine elsewhere too) — R2-proven
static __device__ __forceinline__ bf16x4 pack4(float a, float b, float c, float d) {
    unsigned ua = __builtin_bit_cast(unsigned, a) + 0x8000u;
    unsigned ub = __builtin_bit_cast(unsigned, b) + 0x8000u;
    unsigned uc = __builtin_bit_cast(unsigned, c) + 0x8000u;
    unsigned ud = __builtin_bit_cast(unsigned, d) + 0x8000u;
    u32x2 t;
    t[0] = (ua >> 16) | (ub & 0xFFFF0000u);
    t[1] = (uc >> 16) | (ud & 0xFFFF0000u);
    return __builtin_bit_cast(bf16x4, t);
}

// truncating pack via byte-perm — softmax P only (num & denom share truncation)
static __device__ __forceinline__ bf16x4 pack4_trunc(float a, float b, float c, float d) {
    unsigned ea = __builtin_bit_cast(unsigned, a);
    unsigned eb = __builtin_bit_cast(unsigned, b);
    unsigned ec = __builtin_bit_cast(unsigned, c);
    unsigned ed = __builtin_bit_cast(unsigned, d);
    u32x2 t;
    t[0] = __builtin_amdgcn_perm(eb, ea, 0x07060302u);
    t[1] = __builtin_amdgcn_perm(ed, ec, 0x07060302u);
    return __builtin_bit_cast(bf16x4, t);
}

// wave-level stats reduce: 6 shfl_down pairs, one LDS slot per wave, ONE barrier.
static __device__ __forceinline__ void stats_reduce(float s1, float s2, float* r1, float* r2,
                                                    int tid, int lane, int wv,
                                                    float* __restrict__ stats, int b) {
    #pragma unroll
    for (int o = 32; o > 0; o >>= 1) {
        s1 += __shfl_down(s1, o, 64);
        s2 += __shfl_down(s2, o, 64);
    }
    if (lane == 0) { r1[wv] = s1; r2[wv] = s2; }
    __syncthreads();
    if (tid == 0) {
        float t1 = 0.f, t2 = 0.f;
        #pragma unroll
        for (int i = 0; i < 8; ++i) { t1 += r1[i]; t2 += r2[i]; }
        atomicAdd(&stats[b*2], t1); atomicAdd(&stats[b*2+1], t2);
    }
}

// ---------------- QKV: MFMA GEMM (+fused LN2+roll); LA: LDS-staged weights + global init ----------------
// grid = 416 blocks, 512 threads (8 waves: 4 row-subtiles x 2 nt-halves)
template<bool LA>
__global__ __launch_bounds__(512) void qkv_kernel(const float* __restrict__ src,
        const float* __restrict__ st, const float* __restrict__ g, const float* __restrict__ be,
        const float* __restrict__ qw,       // LA: raw f32 [C][3C]
        const short* __restrict__ wfq,      // !LA: global bf16 frags (3072 units)
        const float* __restrict__ bias,
        short* __restrict__ qf, short* __restrict__ kf, short* __restrict__ vf,
        float* __restrict__ stats,
        // LA-only: sources for downstream weight-frag conversion
        const float* __restrict__ pA, const float* __restrict__ w1A, const float* __restrict__ w2A,
        const float* __restrict__ qwB, const float* __restrict__ pB,
        const float* __restrict__ w1B, const float* __restrict__ w2B,
        short* __restrict__ wfg) {
    __shared__ short wqs[LA ? 12288 : 64];   // 24 KB weight frags (LA only)
    __shared__ short os[64*196];             // 24.5 KB transpose buffer [pos][ch]
    int tid = threadIdx.x;
    int b = blockIdx.x / 52;
    int r0 = (blockIdx.x % 52) * 64;
    const float* xb = src + (size_t)b*CTV;

    int lane = tid & 63; int wv = tid >> 6;     // 0..7
    int rs = wv & 3; int gsel = wv >> 2;        // row subtile / nt-half
    int l15 = lane & 15; int quad = lane >> 4;
    int r = r0 + rs*16 + l15;
    int rc = (r < TV) ? r : TV-1;
    int t = rc / Vv; int vv = rc - t*Vv;
    float mean = 0.f, rstd = 0.f; int off;
    if (!LA) {
        mean = st[b*2] * (1.0f/CTV);
        float var = st[b*2+1] * (1.0f/CTV) - mean*mean;
        rstd = rsqrtf(var + EPSF);
        off = ((t+2)&15)*Vv + vv;       // roll(-2): read source at t+2
    } else off = rc;

    // x fragment FIRST: issue global loads early
    bf16x4 xf[4];
    #pragma unroll
    for (int kc = 0; kc < 4; ++kc) {
        #pragma unroll
        for (int j = 0; j < 4; ++j) {
            int idx = (kc*16 + quad*4 + j)*TV + off;
            float x0 = xb[idx];
            if (!LA) x0 = (x0 - mean)*rstd*g[idx] + be[idx];
            xf[kc][j] = f2bf(x0);
        }
    }

    if constexpr (LA) {
        // own weights -> LDS frags
        for (int fs = tid; fs < 3072; fs += 512) {
            int nt = fs >> 8; int kc = (fs >> 6) & 3; int ln = fs & 63;
            int li = ln & 15; int q = ln >> 4;
            bf16x4 o;
            #pragma unroll
            for (int j = 0; j < 4; ++j) o[j] = f2bf(qw[(kc*16 + q*4 + j)*192 + nt*16 + li]);
            *((bf16x4*)&wqs[fs*4]) = o;
        }
        if (blockIdx.x == 0 && tid < 64) stats[tid] = 0.f;
        // downstream weight frags -> GLOBAL (done once; consumed by later kernels via L2)
        for (int i = blockIdx.x*512 + tid; i < WFU; i += 416*512) {
            int s, kind; const float* sp;
            if (i < 1024)       { s = i;        sp = pA;  kind = 0; }
            else if (i < 5120)  { s = i-1024;   sp = w1A; kind = 1; }
            else if (i < 9216)  { s = i-5120;   sp = w2A; kind = 2; }
            else if (i < 12288) { s = i-9216;   sp = qwB; kind = 3; }
            else if (i < 13312) { s = i-12288;  sp = pB;  kind = 0; }
            else if (i < 17408) { s = i-13312;  sp = w1B; kind = 1; }
            else                { s = i-17408;  sp = w2B; kind = 2; }
            int nt = s >> 8; int kc = (s >> 6) & 3; int ln = s & 63;
            int li = ln & 15; int q = ln >> 4;
            bf16x4 o;
            #pragma unroll
            for (int j = 0; j < 4; ++j) {
                int sidx;
                if (kind == 0)      sidx = (kc*16 + q*4 + j)*64  + nt*16 + li;
                else if (kind == 1) sidx = (kc*16 + q*4 + j)*256 + nt*16 + li;
                else if (kind == 2) sidx = (nt*16 + q*4 + j)*64  + kc*16 + li;
                else                sidx = (kc*16 + q*4 + j)*192 + nt*16 + li;
                o[j] = f2bf(sp[sidx]);
            }
            *((bf16x4*)&wfg[i*4]) = o;
        }
        // frag pad constants (all addresses attn reads must be DEFINED)
        for (int i = blockIdx.x*512 + tid; i < NBWH*1664; i += 416*512) {
            int bwh = i / 1664; int rest = i % 1664;
            int nt = rest >> 5; int u = rest & 31;
            size_t base = (size_t)bwh*FRAG_BWH + nt*256;
            *((u32x2*)&qf[base + (32+u)*4]) = (u32x2){0u, 0u};
            *((u32x2*)&kf[base + (32+u)*4]) = (u32x2){0u, 0u};
            int vlane = (u>>3)*16 + 8 + (u&7);
            short v = ((u&7) == 0) ? (short)0x3F80 : (short)0;
            bf16x4 vv4 = {v,v,v,v};
            *((bf16x4*)&vf[base + vlane*4]) = vv4;
            if (nt == 51) {
                bf16x4 z4 = {0,0,0,0};
                if (u < 4) {
                    *((bf16x4*)&kf[base + (12+u)*4]) = z4;
                    *((bf16x4*)&qf[base + (12+u)*4]) = z4;
                } else if (u < 8) {
                    *((bf16x4*)&kf[base + (24+u)*4]) = z4;
                    *((bf16x4*)&qf[base + (24+u)*4]) = z4;
                } else if (u < 16) {
                    *((bf16x4*)&vf[base + (40+u)*4]) = z4;
                }
            }
        }
        __syncthreads();   // wqs ready
    }

    f32x4 accv[6];
    #pragma unroll
    for (int ntl = 0; ntl < 6; ++ntl) {
        int nt = gsel*6 + ntl;
        float4 bb = *((const float4*)&bias[nt*16 + quad*4]);
        f32x4 acc = {bb.x, bb.y, bb.z, bb.w};
        #pragma unroll
        for (int kc = 0; kc < 4; ++kc) {
            bf16x4 wf2;
            if constexpr (LA) wf2 = *((const bf16x4*)&wqs[((nt*4 + kc)*64 + lane)*4]);
            else              wf2 = *((const bf16x4*)&wfq[((size_t)((nt*4 + kc)*64 + lane))*4]);
            acc = __builtin_amdgcn_mfma_f32_16x16x16bf16_1k(wf2, xf[kc], acc, 0, 0, 0);
        }
        accv[ntl] = acc;
    }

    // transpose to LDS: os[pos*196 + ch], ch = nt*16 + quad*4 + j
    int pos = rs*16 + l15;
    #pragma unroll
    for (int ntl = 0; ntl < 6; ++ntl) {
        int nt = gsel*6 + ntl;
        f32x4 a = accv[ntl];
        bf16x4 pk = (nt < 4) ? pack4(a[0]*QSCALE, a[1]*QSCALE, a[2]*QSCALE, a[3]*QSCALE)
                             : pack4(a[0], a[1], a[2], a[3]);
        *((bf16x4*)&os[pos*196 + nt*16 + quad*4]) = pk;
    }
    __syncthreads();

    // store phase: frag-ordered outputs; 8 waves -> h = wv for q/k
    int pp = tid & 63;
    int rr = r0 + pp;
    bool pv = rr < TV;
    int rrc = pv ? rr : TV-1;
    int t4 = rrc / Vv; int vv4 = rrc - t4*Vv;
    int n2 = (t4 & 3)*Vv + vv4;
    int nt2 = n2 >> 4; int l15n = n2 & 15;
    int wbase = (b*NW + (t4 >> 2))*Hh;
    if (pv) {
        int h = wv;
        size_t fb = ((size_t)(wbase+h)*52 + nt2)*256;
        bf16x4 q0 = *((const bf16x4*)&os[pp*196 + h*8]);
        bf16x4 q1 = *((const bf16x4*)&os[pp*196 + h*8 + 4]);
        *((bf16x4*)&qf[fb + l15n*4])        = q0;
        *((bf16x4*)&qf[fb + (16 + l15n)*4]) = q1;
        bf16x4 k0 = *((const bf16x4*)&os[pp*196 + 64 + h*8]);
        bf16x4 k1 = *((const bf16x4*)&os[pp*196 + 64 + h*8 + 4]);
        *((bf16x4*)&kf[fb + l15n*4])        = k0;
        *((bf16x4*)&kf[fb + (16 + l15n)*4]) = k1;
    }
    // v store: vectorized 4-row quads (828 % 4 == 0 so quads never straddle windows)
    #pragma unroll
    for (int u2 = 0; u2 < 2; ++u2) {
        int unit = u2*512 + tid;
        int rq = unit >> 6;          // 0..15
        int hd = unit & 63;
        int r4 = r0 + rq*4;
        if (r4 < TV) {
            int w = r4 / Nn;
            int n = r4 - w*Nn;
            int nt2v = n >> 4; int quadv = (n >> 2) & 3;
            int h = hd >> 3; int d = hd & 7;
            int posb = rq*4;
            bf16x4 vo;
            vo[0] = os[(posb+0)*196 + 128 + hd];
            vo[1] = os[(posb+1)*196 + 128 + hd];
            vo[2] = os[(posb+2)*196 + 128 + hd];
            vo[3] = os[(posb+3)*196 + 128 + hd];
            *((bf16x4*)&vf[((((size_t)(b*NW + w)*Hh + h)*52 + nt2v)*64 + quadv*16 + d)*4]) = vo;
        }
    }
}

// ---------------- Flash MFMA attention: aq prefetch + mask-free main loop (nt=51 peeled) ----------------
// grid = 256 blocks, 1024 threads (16 waves; wave wv owns m-tiles wv+16*i)
__global__ __launch_bounds__(1024) void attn_kernel(const short* __restrict__ qf,
        const short* __restrict__ kf, const short* __restrict__ vf,
        short* __restrict__ att) {
    __shared__ short ks2[FRAG_BWH];   // 26.6 KB
    __shared__ short vs2[FRAG_BWH];   // 26.6 KB
    int bwh = blockIdx.x;
    int tid = threadIdx.x;
    int lane = tid & 63;
    int wv = tid >> 6;
    int quad = lane >> 4;
    int l15 = lane & 15;

    // aq prefetch FIRST: Q-frag loads issue before staging so HBM latency hides under it
    int nm = (wv < 4) ? 4 : 3;
    const short* qbase = qf + (size_t)bwh*FRAG_BWH;
    bf16x4 aq[4];
    f32x4 oacc[4];
    #pragma unroll
    for (int i = 0; i < 4; ++i) {
        aq[i] = (bf16x4){0,0,0,0};
        oacc[i] = (f32x4){0.f,0.f,0.f,0.f};
        if (i < nm)
            aq[i] = *(const bf16x4*)(qbase + ((wv + 16*i)*256 + lane*4));
    }

    {
        const u32x4* kg = (const u32x4*)(kf + (size_t)bwh*FRAG_BWH);
        const u32x4* vg = (const u32x4*)(vf + (size_t)bwh*FRAG_BWH);
        u32x4* kd = (u32x4*)ks2; u32x4* vd = (u32x4*)vs2;
        for (int idx = tid; idx < 1664; idx += 1024) { kd[idx] = kg[idx]; vd[idx] = vg[idx]; }
    }
    __syncthreads();

    // main loop: nt = 0..50, no pad mask on the P chain
    #pragma unroll 1
    for (int nt = 0; nt < 51; ++nt) {
        bf16x4 ak = *(const bf16x4*)&ks2[nt*256 + lane*4];
        bf16x4 av = *(const bf16x4*)&vs2[nt*256 + lane*4];
        #pragma unroll
        for (int i = 0; i < 4; ++i) {
            if (i < nm) {
                f32x4 s = __builtin_amdgcn_mfma_f32_16x16x16bf16_1k(
                              ak, aq[i], (f32x4){0.f,0.f,0.f,0.f}, 0, 0, 0);
                bf16x4 pb = pack4_trunc(__builtin_amdgcn_exp2f(s[0]), __builtin_amdgcn_exp2f(s[1]),
                                        __builtin_amdgcn_exp2f(s[2]), __builtin_amdgcn_exp2f(s[3]));
                oacc[i] = __builtin_amdgcn_mfma_f32_16x16x16bf16_1k(av, pb, oacc[i], 0, 0, 0);
            }
        }
    }
    // peeled tail: nt = 51 with pad-key mask (keys n=828..831 live in quad 3)
    {
        bf16x4 ak = *(const bf16x4*)&ks2[51*256 + lane*4];
        bf16x4 av = *(const bf16x4*)&vs2[51*256 + lane*4];
        bool mask = (quad == 3);
        #pragma unroll
        for (int i = 0; i < 4; ++i) {
            if (i < nm) {
                f32x4 s = __builtin_amdgcn_mfma_f32_16x16x16bf16_1k(
                              ak, aq[i], (f32x4){0.f,0.f,0.f,0.f}, 0, 0, 0);
                bf16x4 pb = pack4_trunc(__builtin_amdgcn_exp2f(s[0]), __builtin_amdgcn_exp2f(s[1]),
                                        __builtin_amdgcn_exp2f(s[2]), __builtin_amdgcn_exp2f(s[3]));
                if (mask) pb = (bf16x4){0,0,0,0};
                oacc[i] = __builtin_amdgcn_mfma_f32_16x16x16bf16_1k(av, pb, oacc[i], 0, 0, 0);
            }
        }
    }
    int h = bwh & 7; int bw = bwh >> 3;
    #pragma unroll
    for (int i = 0; i < 4; ++i) {
        if (i < nm) {
            float ls = __shfl(oacc[i][0], 32 + l15, 64);   // l-sum = O row 8
            float inv = 1.f / ls;
            int m = (wv + 16*i)*16 + l15;
            if (quad < 2 && m < Nn) {
                bf16x4 ov = pack4(oacc[i][0]*inv, oacc[i][1]*inv,
                                  oacc[i][2]*inv, oacc[i][3]*inv);
                *((bf16x4*)&att[((size_t)bw*Nn + m)*Cc + h*DH + quad*4]) = ov;
            }
        }
    }
}

// ---------------- Proj: global weight frags; residual hoist; shuffle stats reduce ----------------
__global__ __launch_bounds__(512) void proj_kernel(const short* __restrict__ att,
        const short* __restrict__ wfp, const float* __restrict__ bo,
        const float* __restrict__ resid,
        const float* __restrict__ st, const float* __restrict__ g, const float* __restrict__ be,
        float* __restrict__ out, float* __restrict__ stats) {
    __shared__ float r1[8], r2[8];
    int tid = threadIdx.x;
    int b = blockIdx.x / 52;
    int r0 = (blockIdx.x % 52) * 64;
    const float* xb = resid + (size_t)b*CTV;

    int lane = tid & 63; int wv = tid >> 6;
    int rs = wv & 3; int gsel = wv >> 2;
    int l15 = lane & 15; int quad = lane >> 4;
    int r = r0 + rs*16 + l15;
    bool valid = r < TV;
    int rc = valid ? r : TV-1;
    int t = rc / Vv; int vv = rc - t*Vv;
    int n = (t & 3)*Vv + vv;
    int bw = b*NW + (t >> 2);

    // LN params + residual offset EARLY (so residual loads can hoist)
    float mean = 0.f, rstd = 0.f; int off;
    if (st) {
        mean = st[b*2] * (1.0f/CTV);
        float var = st[b*2+1] * (1.0f/CTV) - mean*mean;
        rstd = rsqrtf(var + EPSF);
        off = ((t+2)&15)*Vv + vv;
    } else off = rc;

    // att loads (MFMA A-operand)
    const short* arow = att + ((size_t)bw*Nn + n)*Cc;
    bf16x4 af[4];
    #pragma unroll
    for (int kc = 0; kc < 4; ++kc)
        af[kc] = *((const bf16x4*)&arow[kc*16 + quad*4]);

    // residual prefetch: independent loads issued BEFORE the MFMA chain
    float xr[8], gr[8], ber[8];
    #pragma unroll
    for (int ntl = 0; ntl < 2; ++ntl) {
        #pragma unroll
        for (int j = 0; j < 4; ++j) {
            int c_out = (gsel*2 + ntl)*16 + quad*4 + j;
            int ridx = c_out*TV + off;
            int u = ntl*4 + j;
            xr[u] = xb[ridx];
            if (st) { gr[u] = g[ridx]; ber[u] = be[ridx]; }
        }
    }

    f32x4 acc[2];
    #pragma unroll
    for (int ntl = 0; ntl < 2; ++ntl) {
        int nt = gsel*2 + ntl;
        float4 bb = *((const float4*)&bo[nt*16 + quad*4]);
        acc[ntl] = (f32x4){bb.x, bb.y, bb.z, bb.w};
        #pragma unroll
        for (int kc = 0; kc < 4; ++kc) {
            bf16x4 wf2 = *((const bf16x4*)&wfp[((size_t)((nt*4 + kc)*64 + lane))*4]);
            acc[ntl] = __builtin_amdgcn_mfma_f32_16x16x16bf16_1k(wf2, af[kc], acc[ntl], 0, 0, 0);
        }
    }

    float s1 = 0.f, s2 = 0.f;
    if (valid) {
        #pragma unroll
        for (int ntl = 0; ntl < 2; ++ntl) {
            int nt = gsel*2 + ntl;
            #pragma unroll
            for (int j = 0; j < 4; ++j) {
                int c_out = nt*16 + quad*4 + j;
                int u = ntl*4 + j;
                float xv = xr[u];
                if (st) xv = (xv - mean)*rstd*gr[u] + ber[u];
                float val = acc[ntl][j] + xv;
                out[(size_t)b*CTV + (size_t)c_out*TV + r] = val;
                s1 += val; s2 += val*val;
            }
        }
    }
    stats_reduce(s1, s2, r1, r2, tid, lane, wv, stats, b);
}

// ---------------- LayerNorm apply (+roll) — final output only; 4 elems/thread ----------------
__global__ void ln_apply_kernel(const float* __restrict__ x,
                                const float* __restrict__ g,
                                const float* __restrict__ be,
                                const float* __restrict__ stats,
                                float* __restrict__ out) {
    int i4 = (blockIdx.x*256 + threadIdx.x) * 4;
    if (i4 >= S) return;
    int b = i4 / CTV; int r = i4 % CTV;
    int c = r / TV; int q2 = r % TV; int t = q2 / Vv; int vv = q2 - t*Vv;
    float mean = stats[b*2] * (1.0f/CTV);
    float var  = stats[b*2+1] * (1.0f/CTV) - mean*mean;
    float rstd = rsqrtf(var + EPSF);
    float4 xv = *((const float4*)&x[i4]);
    float vals[4] = {xv.x, xv.y, xv.z, xv.w};
    size_t obase = (size_t)(b*Cc + c)*Tt;
    #pragma unroll
    for (int j = 0; j < 4; ++j) {
        float val = (vals[j]-mean)*rstd*g[r+j] + be[r+j];
        int tout = (t - 2 + Tt) & 15;   // roll(-2)
        out[(obase + tout)*Vv + vv] = val;
        if (++vv == Vv) { vv = 0; ++t; }
    }
}

// ---------------- FFN: global weight frags; shuffle stats reduce ----------------
__global__ __launch_bounds__(512) void ffn_kernel(const float* __restrict__ xin,
        const float* __restrict__ st, const float* __restrict__ g, const float* __restrict__ be,
        const short* __restrict__ wf1g, const float* __restrict__ b1,
        const short* __restrict__ wf2g, const float* __restrict__ b2,
        float* __restrict__ out, float* __restrict__ stats) {
    __shared__ short xsf[4096];     // 8 KB
    __shared__ float r1s[8], r2s[8];
    int tid = threadIdx.x;
    int b = blockIdx.x / 52;
    int r0 = (blockIdx.x % 52) * 64;
    const float* xb = xin + (size_t)b*CTV;
    float mean = st[b*2] * (1.0f/CTV);
    float var  = st[b*2+1] * (1.0f/CTV) - mean*mean;
    float rstd = rsqrtf(var + EPSF);

    // x staging (LN1 fused)
    for (int s2 = tid; s2 < 1024; s2 += 512) {
        int wv2 = s2 >> 8; int kc = (s2 >> 6) & 3; int ln = s2 & 63;
        int l15 = ln & 15; int quad = ln >> 4;
        int r = r0 + wv2*16 + l15; if (r >= TV) r = TV-1;
        bf16x4 f;
        #pragma unroll
        for (int j = 0; j < 4; ++j) {
            int idx = (kc*16 + quad*4 + j)*TV + r;
            f[j] = f2bf((xb[idx] - mean)*rstd*g[idx] + be[idx]);
        }
        *((bf16x4*)&xsf[s2*4]) = f;
    }
    __syncthreads();

    int lane = tid & 63; int wv = tid >> 6;
    int rs = wv & 3; int gsel = wv >> 2;
    int l15 = lane & 15; int quad = lane >> 4;
    bf16x4 xf[4];
    #pragma unroll
    for (int kc = 0; kc < 4; ++kc)
        xf[kc] = *((const bf16x4*)&xsf[((rs*4 + kc)*64 + lane)*4]);

    f32x4 oacc[2];
    #pragma unroll
    for (int ctl = 0; ctl < 2; ++ctl) oacc[ctl] = (f32x4){0.f,0.f,0.f,0.f};

    for (int nt = 0; nt < 16; ++nt) {
        float4 bb = *((const float4*)&b1[nt*16 + quad*4]);
        f32x4 acc = {bb.x, bb.y, bb.z, bb.w};
        #pragma unroll
        for (int kc = 0; kc < 4; ++kc) {
            bf16x4 wfv = *((const bf16x4*)&wf1g[((size_t)((nt*4 + kc)*64 + lane))*4]);
            acc = __builtin_amdgcn_mfma_f32_16x16x16bf16_1k(wfv, xf[kc], acc, 0, 0, 0);
        }
        bf16x4 pf = pack4(fmaxf(acc[0], 0.f), fmaxf(acc[1], 0.f),
                          fmaxf(acc[2], 0.f), fmaxf(acc[3], 0.f));
        #pragma unroll
        for (int ctl = 0; ctl < 2; ++ctl) {
            int ct = gsel*2 + ctl;
            bf16x4 wfv2 = *((const bf16x4*)&wf2g[((size_t)((nt*4 + ct)*64 + lane))*4]);
            oacc[ctl] = __builtin_amdgcn_mfma_f32_16x16x16bf16_1k(wfv2, pf, oacc[ctl], 0, 0, 0);
        }
    }
    int r = r0 + rs*16 + l15;
    float s1 = 0.f, s2v = 0.f;
    if (r < TV) {
        #pragma unroll
        for (int ctl = 0; ctl < 2; ++ctl) {
            int ct = gsel*2 + ctl;
            #pragma unroll
            for (int j = 0; j < 4; ++j) {
                int c_out = ct*16 + quad*4 + j;
                int idx = c_out*TV + r;
                float xv = (xb[idx] - mean)*rstd*g[idx] + be[idx];
                float val = oacc[ctl][j] + b2[c_out] + xv;
                out[(size_t)b*CTV + idx] = val;
                s1 += val; s2v += val*val;
            }
        }
    }
    stats_reduce(s1, s2v, r1s, r2s, tid, lane, wv, stats, b);
}

extern "C" void kernel_launch(void* const* d_in, const int* in_sizes, int n_in,
                              void* d_out, int out_size, void* d_ws, size_t ws_size,
                              hipStream_t stream) {
    const float* xin = (const float*)d_in[0];

    float* bufA  = (float*)d_ws;
    float* bufB  = bufA + S;
    float* stats = bufB + S;                        // 64 floats
    short* qf    = (short*)(stats + 64);            // [NBWH][52][64][4]
    short* kf    = qf + (size_t)NBWH*FRAG_BWH;
    short* vf    = kf + (size_t)NBWH*FRAG_BWH;
    short* att   = vf + (size_t)NBWH*FRAG_BWH;      // [32][Nn][64] bf16
    short* wfg   = att + (size_t)32*Nn*64;          // 21504 bf16x4 weight-frag units

    const float* A0  = (const float*)d_in[1];
    const float* A1  = (const float*)d_in[2];
    const float* A2  = (const float*)d_in[3];
    const float* A3  = (const float*)d_in[4];
    const float* A4  = (const float*)d_in[5];
    const float* A5  = (const float*)d_in[6];
    const float* A6  = (const float*)d_in[7];
    const float* A7  = (const float*)d_in[8];
    const float* A8  = (const float*)d_in[9];
    const float* A9  = (const float*)d_in[10];
    const float* A10 = (const float*)d_in[11];
    const float* A11 = (const float*)d_in[12];
    const float* B0  = (const float*)d_in[13];
    const float* B1  = (const float*)d_in[14];
    const float* B2  = (const float*)d_in[15];
    const float* B3  = (const float*)d_in[16];
    const float* B4  = (const float*)d_in[17];
    const float* B5  = (const float*)d_in[18];
    const float* B6  = (const float*)d_in[19];
    const float* B7  = (const float*)d_in[20];
    const float* B8  = (const float*)d_in[21];
    const float* B9  = (const float*)d_in[22];
    const float* B10 = (const float*)d_in[23];
    const float* B11 = (const float*)d_in[24];

    float* st1a = stats + 0;
    float* st2a = stats + 16;
    float* st1b = stats + 32;
    float* st2b = stats + 48;

    // global frag offsets (shorts)
    const short* wprojA = wfg;              // units @0
    const short* w1Ag   = wfg + 4096;       // @1024
    const short* w2Ag   = wfg + 20480;      // @5120
    const short* wqkvB  = wfg + 36864;      // @9216
    const short* wprojB = wfg + 49152;      // @12288
    const short* w1Bg   = wfg + 53248;      // @13312
    const short* w2Bg   = wfg + 69632;      // @17408

    // ---- block A (input raw) ----
    qkv_kernel<true><<<Bb*52, 512, 0, stream>>>(xin, nullptr, nullptr, nullptr,
                                          A0, nullptr, A1, qf, kf, vf, stats,
                                          A2, A4, A6, B0, B2, B4, B6, wfg);
    attn_kernel<<<NBWH, 1024, 0, stream>>>(qf, kf, vf, att);
    proj_kernel<<<Bb*52, 512, 0, stream>>>(att, wprojA, A3, xin,
                                           nullptr, nullptr, nullptr, bufB, st1a);
    ffn_kernel<<<Bb*52, 512, 0, stream>>>(bufB, st1a, A8, A9,
                                          w1Ag, A5, w2Ag, A7, bufB, st2a);
    // ---- block B (input = LN_a2(bufB) rolled, fused into consumers) ----
    qkv_kernel<false><<<Bb*52, 512, 0, stream>>>(bufB, st2a, A10, A11,
                                          nullptr, wqkvB, B1, qf, kf, vf, stats,
                                          nullptr, nullptr, nullptr, nullptr,
                                          nullptr, nullptr, nullptr, nullptr);
    attn_kernel<<<NBWH, 1024, 0, stream>>>(qf, kf, vf, att);
    proj_kernel<<<Bb*52, 512, 0, stream>>>(att, wprojB, B3, bufB,
                                           st2a, A10, A11, bufA, st1b);
    ffn_kernel<<<Bb*52, 512, 0, stream>>>(bufA, st1b, B8, B9,
                                          w1Bg, B5, w2Bg, B7, bufA, st2b);
    // ---- final LN_b2 + roll -> d_out ----
    ln_apply_kernel<<<(S/4+255)/256, 256, 0, stream>>>(bufA, B10, B11, st2b, (float*)d_out);
}